// Round 2
// baseline (164.847 us; speedup 1.0000x reference)
//
#include <hip/hip_runtime.h>
#include <math.h>

// Problem constants (match reference setup_inputs)
#define B_N   8192      // samples
#define Z_D   128       // feature dim
#define P_N   93        // proxies
#define NCLS  62        // classes
#define A_N   2730      // anchors: arange(0, 8189, 3)
#define BCAP  256       // class-bucket capacity (max count ~180 at +10 sigma)
#define TWO_EPS   2e-6f
#define ZEPS2     (128.0f * 1e-6f * 1e-6f)

__device__ __forceinline__ float wave_sum(float v) {
#pragma unroll
  for (int off = 1; off < 64; off <<= 1) v += __shfl_xor(v, off, 64);
  return v;
}
__device__ __forceinline__ float wave_min(float v) {
#pragma unroll
  for (int off = 1; off < 64; off <<= 1) v = fminf(v, __shfl_xor(v, off, 64));
  return v;
}

// --- kP: normalize proxies, per-proxy norms/sums, zero acc + bucket counts --
__global__ void kP(const float* __restrict__ prox, float* __restrict__ prxn,
                   float* __restrict__ pp, float* __restrict__ sp,
                   float* __restrict__ acc, int* __restrict__ cnt) {
  const int row = blockIdx.x;            // 0..92
  const int lane = threadIdx.x;          // 0..63
  float a = prox[row * Z_D + lane];
  float b = prox[row * Z_D + 64 + lane];
  float s = wave_sum(a + b);
  float q = wave_sum(a * a + b * b);
  float inv = 1.0f / fmaxf(sqrtf(q), 1e-12f);
  prxn[row * Z_D + lane] = a * inv;
  prxn[row * Z_D + 64 + lane] = b * inv;
  if (lane == 0) {
    pp[row] = q * inv * inv;   // ||p_hat||^2
    sp[row] = s * inv;         // sum(p_hat)
    if (row < NCLS) cnt[row] = 0;
    if (row == 0) acc[0] = 0.0f;
  }
}

// --- kZ: per-sample sums, class lookup, bucket insert ----------------------
__global__ void kZ(const float* __restrict__ z, const int* __restrict__ y_idx,
                   const int* __restrict__ y_map,
                   float* __restrict__ zz, float* __restrict__ sz,
                   float* __restrict__ w, int* __restrict__ yrel,
                   int* __restrict__ cnt, int* __restrict__ bucket) {
  const int wid = (int)((blockIdx.x * blockDim.x + threadIdx.x) >> 6);
  const int lane = threadIdx.x & 63;
  if (wid >= B_N) return;
  float a = z[wid * Z_D + lane];
  float b = z[wid * Z_D + 64 + lane];
  float s = wave_sum(a + b);
  float q = wave_sum(a * a + b * b);
  if (lane == 0) {
    zz[wid] = q;
    sz[wid] = s;
    w[wid] = q - TWO_EPS * s;            // zz - 2*eps*sz  (per-j distance part)
    int yi = y_idx[wid];
    int r = 0;                            // argmax over all-false = 0
    for (int m = 0; m < NCLS; ++m) {
      if (y_map[m] == yi) { r = m; break; }
    }
    yrel[wid] = r;
    int pos = atomicAdd(&cnt[r], 1);
    if (pos < BCAP) bucket[r * BCAP + pos] = wid;   // unordered within class
  }
}

// --- kG: G[k][j] = p_hat_k . z_j (row-major G + transposed GT, stride 93) --
// grid (32 j-blocks, 12 k-tiles), block 256; proxy tile staged in LDS.
__global__ void kG(const float* __restrict__ z, const float* __restrict__ prxn,
                   float* __restrict__ G, float* __restrict__ GT) {
  __shared__ float pt[8 * Z_D];                    // 4 KB proxy tile
  const int tid = threadIdx.x;
  const int j = blockIdx.x * 256 + tid;            // 0..8191
  const int k0 = blockIdx.y * 8;                   // 0,8,...,88
  // stage 8 proxy rows (1024 floats) — prxn padded to 96 rows so OOB is safe
  ((float4*)pt)[tid] = ((const float4*)(prxn + (size_t)k0 * Z_D))[tid];
  __syncthreads();
  float acc[8];
#pragma unroll
  for (int kk = 0; kk < 8; ++kk) acc[kk] = 0.0f;
  const float* __restrict__ zrow = z + (size_t)j * Z_D;
  for (int i4 = 0; i4 < Z_D; i4 += 4) {
    const float4 zv = *(const float4*)(zrow + i4);
#pragma unroll
    for (int kk = 0; kk < 8; ++kk) {
      const float4 pv = *(const float4*)(pt + kk * Z_D + i4);  // LDS broadcast
      acc[kk] += zv.x * pv.x + zv.y * pv.y + zv.z * pv.z + zv.w * pv.w;
    }
  }
#pragma unroll
  for (int kk = 0; kk < 8; ++kk) {
    const int k = k0 + kk;
    if (k < P_N) {
      G[(size_t)k * B_N + j] = acc[kk];            // coalesced over j
      GT[(size_t)j * P_N + k] = acc[kk];           // scattered, 3 MB total
    }
  }
}

// --- kC: one wave per anchor (argmin proxy -> bucket argmax -> logsumexp) --
__global__ void kC(const float* __restrict__ zz, const float* __restrict__ sz,
                   const float* __restrict__ w, const int* __restrict__ yrel,
                   const float* __restrict__ pp, const float* __restrict__ sp,
                   const float* __restrict__ G, const float* __restrict__ GT,
                   const int* __restrict__ cnt, const int* __restrict__ bucket,
                   float* __restrict__ acc) {
  const int wid = (int)((blockIdx.x * blockDim.x + threadIdx.x) >> 6);
  const int lane = threadIdx.x & 63;
  if (wid >= A_N) return;
  const int i = 3 * wid;                 // anchor sample index
  const float zzi = zz[i], szi = sz[i];
  const int cls = yrel[i];
  const int k2 = lane + 64;

  // --- step a: nearest proxy to anchor (argmin, first-index tie-break) ---
  const float* __restrict__ GTi = GT + (size_t)i * P_N;
  float v1 = fmaxf(zzi + pp[lane] - 2.0f * GTi[lane] +
                   TWO_EPS * (szi - sp[lane]) + ZEPS2, 0.0f);
  int i1 = lane;
  if (k2 < P_N) {
    float v2 = fmaxf(zzi + pp[k2] - 2.0f * GTi[k2] +
                     TWO_EPS * (szi - sp[k2]) + ZEPS2, 0.0f);
    if (v2 < v1) { v1 = v2; i1 = k2; }
  }
#pragma unroll
  for (int off = 1; off < 64; off <<= 1) {
    float ov = __shfl_xor(v1, off, 64);
    int oi = __shfl_xor(i1, off, 64);
    if (ov < v1 || (ov == v1 && oi < i1)) { v1 = ov; i1 = oi; }
  }
  const int p = i1;

  // --- step b: hardest positive among same-class suffix (class bucket) ---
  const float cp = pp[p] + TWO_EPS * sp[p] + ZEPS2;  // per-proxy constant
  const float* __restrict__ Grow = G + (size_t)p * B_N;
  const int n = min(cnt[cls], BCAP);
  const int* __restrict__ bk = bucket + cls * BCAP;
  float best = -INFINITY;
  int bestj = 0x7fffffff;
  for (int t = lane; t < n; t += 64) {
    const int j = bk[t];
    if (j >= i) {
      const float v = fmaxf(cp + w[j] - 2.0f * Grow[j], 0.0f);
      if (v > best || (v == best && j < bestj)) { best = v; bestj = j; }
    }
  }
#pragma unroll
  for (int off = 1; off < 64; off <<= 1) {
    float ov = __shfl_xor(best, off, 64);
    int oj = __shfl_xor(bestj, off, 64);
    if (ov > best || (ov == best && oj < bestj)) { best = ov; bestj = oj; }
  }
  const float Dp = sqrtf(best);
  const int jp = bestj;

  // --- step c: logsumexp(-D_n) over proxies ---
  const float zzj = zz[jp], szj = sz[jp];
  const float* __restrict__ GTj = GT + (size_t)jp * P_N;
  float d1 = sqrtf(fmaxf(zzj + pp[lane] - 2.0f * GTj[lane] +
                         TWO_EPS * (szj - sp[lane]) + ZEPS2, 0.0f));
  float d2 = INFINITY;
  if (k2 < P_N)
    d2 = sqrtf(fmaxf(zzj + pp[k2] - 2.0f * GTj[k2] +
                     TWO_EPS * (szj - sp[k2]) + ZEPS2, 0.0f));
  const float m = wave_min(fminf(d1, d2));
  float ssum = expf(m - d1) + ((k2 < P_N) ? expf(m - d2) : 0.0f);
  ssum = wave_sum(ssum);
  if (lane == 0) atomicAdd(acc, Dp - m + logf(ssum));
}

// --- kF: mean --------------------------------------------------------------
__global__ void kF(const float* __restrict__ acc, float* __restrict__ out) {
  out[0] = acc[0] * (1.0f / (float)A_N);
}

extern "C" void kernel_launch(void* const* d_in, const int* in_sizes, int n_in,
                              void* d_out, int out_size, void* d_ws, size_t ws_size,
                              hipStream_t stream) {
  const float* z = (const float*)d_in[0];      // [8192,128] f32
  const int* y_idx = (const int*)d_in[1];      // [8192] i32
  const float* prox = (const float*)d_in[2];   // [93,128] f32
  const int* y_map = (const int*)d_in[3];      // [62] i32
  float* out = (float*)d_out;

  // workspace layout (bytes) — total 6,339,588 (fits prior 6.34 MB footprint)
  char* ws = (char*)d_ws;
  float* prxn = (float*)(ws + 0);              // 96*128*4 = 49152 (padded rows)
  float* pp   = (float*)(ws + 49152);          // 93*4 -> 49536
  float* sp   = (float*)(ws + 49536);          // 93*4 -> 49920
  float* zz   = (float*)(ws + 49920);          // 8192*4 -> 82688
  float* sz   = (float*)(ws + 82688);          // 8192*4 -> 115456
  float* w    = (float*)(ws + 115456);         // 8192*4 -> 148224
  int*   yrel = (int*)  (ws + 148224);         // 8192*4 -> 180992
  int*   cnt  = (int*)  (ws + 180992);         // 62*4 -> 181248
  int*   bkt  = (int*)  (ws + 181248);         // 62*256*4 -> 244736
  float* G    = (float*)(ws + 244736);         // 93*8192*4 -> 3292160
  float* GT   = (float*)(ws + 3292160);        // 8192*93*4 -> 6339584
  float* acc  = (float*)(ws + 6339584);        // 4

  kP<<<P_N, 64, 0, stream>>>(prox, prxn, pp, sp, acc, cnt);
  kZ<<<(B_N * 64 + 255) / 256, 256, 0, stream>>>(z, y_idx, y_map, zz, sz, w,
                                                 yrel, cnt, bkt);
  kG<<<dim3(B_N / 256, 96 / 8), 256, 0, stream>>>(z, prxn, G, GT);
  kC<<<(A_N + 3) / 4, 256, 0, stream>>>(zz, sz, w, yrel, pp, sp, G, GT,
                                        cnt, bkt, acc);
  kF<<<1, 1, 0, stream>>>(acc, out);
}

// Round 3
// 108.162 us; speedup vs baseline: 1.5241x; 1.5241x over previous
//
#include <hip/hip_runtime.h>
#include <math.h>

// Problem constants (match reference setup_inputs)
#define B_N   8192      // samples
#define Z_D   128       // feature dim
#define P_N   93        // proxies
#define NCLS  62        // classes
#define A_N   2730      // anchors: arange(0, 8189, 3)
#define BCAP  256       // class-bucket capacity (max expected ~180)
#define GT_S  96        // GT row stride (float4-aligned for k0 multiples of 8)
#define TWO_EPS   2e-6f
#define ZEPS2     (128.0f * 1e-6f * 1e-6f)

__device__ __forceinline__ float wave_sum(float v) {
#pragma unroll
  for (int off = 1; off < 64; off <<= 1) v += __shfl_xor(v, off, 64);
  return v;
}
__device__ __forceinline__ float wave_min(float v) {
#pragma unroll
  for (int off = 1; off < 64; off <<= 1) v = fminf(v, __shfl_xor(v, off, 64));
  return v;
}

// --- kP: normalize proxies, pp/sp, inverse class map, zero acc -------------
// 93 blocks x 64 threads; block 0 additionally builds invmap serially via
// wave shuffles (descending m so the SMALLEST matching m wins = jnp.argmax
// first-occurrence; values absent from y_map stay 0 = argmax of all-false).
__global__ void kP(const float* __restrict__ prox, float* __restrict__ prxn,
                   float* __restrict__ pp, float* __restrict__ sp,
                   const int* __restrict__ y_map, int* __restrict__ invmap,
                   float* __restrict__ acc) {
  const int row = blockIdx.x;            // 0..92
  const int lane = threadIdx.x;          // 0..63
  float a = prox[row * Z_D + lane];
  float b = prox[row * Z_D + 64 + lane];
  float s = wave_sum(a + b);
  float q = wave_sum(a * a + b * b);
  float inv = 1.0f / fmaxf(sqrtf(q), 1e-12f);
  prxn[row * Z_D + lane] = a * inv;
  prxn[row * Z_D + 64 + lane] = b * inv;
  if (lane == 0) {
    pp[row] = q * inv * inv;   // ||p_hat||^2
    sp[row] = s * inv;         // sum(p_hat)
    if (row == 0) acc[0] = 0.0f;
  }
  if (row == 0) {
    const int ym = (lane < NCLS) ? y_map[lane] : 0;
    invmap[lane] = 0;                        // default: argmax(all false)=0
    for (int m = NCLS - 1; m >= 0; --m) {    // descending: first match wins
      const int v = __shfl(ym, m, 64);
      if (lane == 0) invmap[v] = m;          // same wave => ordered stores
    }
  }
}

// --- kB: per-class bucket build + yrel, LDS atomics only -------------------
// 62 blocks x 256; block c claims samples of class c. Every j is claimed by
// exactly one block (r = invmap[y_idx[j]] is deterministic), so yrel is
// fully written. Bucket order is irrelevant (kC tie-breaks on smallest j).
__global__ void kB(const int* __restrict__ y_idx, const int* __restrict__ invmap,
                   int* __restrict__ yrel, int* __restrict__ cnt,
                   int* __restrict__ bucket) {
  __shared__ int lcnt;
  const int c = blockIdx.x;
  if (threadIdx.x == 0) lcnt = 0;
  __syncthreads();
  for (int j = threadIdx.x; j < B_N; j += 256) {
    const int r = invmap[y_idx[j]];
    if (r == c) {
      yrel[j] = r;
      const int pos = atomicAdd(&lcnt, 1);   // LDS atomic — cheap
      if (pos < BCAP) bucket[c * BCAP + pos] = j;
    }
  }
  __syncthreads();
  if (threadIdx.x == 0) cnt[c] = min(lcnt, BCAP);
}

// --- kG: GT[j][k] = p_hat_k . z_j (stride 96) + fused per-row z stats ------
// grid (32 j-blocks, 12 k-tiles) x 256; proxy tile staged in LDS.
__global__ void kG(const float* __restrict__ z, const float* __restrict__ prxn,
                   float* __restrict__ GT, float* __restrict__ zz,
                   float* __restrict__ sz, float* __restrict__ w) {
  __shared__ float pt[8 * Z_D];                    // 4 KB proxy tile
  const int tid = threadIdx.x;
  const int j = blockIdx.x * 256 + tid;            // 0..8191
  const int k0 = blockIdx.y * 8;                   // 0,8,...,88
  // prxn padded to 96 rows; rows 93..95 are garbage but their results are
  // stored into GT columns 93..95 which are never read.
  ((float4*)pt)[tid] = ((const float4*)(prxn + (size_t)k0 * Z_D))[tid];
  __syncthreads();
  float acc[8];
#pragma unroll
  for (int kk = 0; kk < 8; ++kk) acc[kk] = 0.0f;
  float s = 0.0f, q = 0.0f;
  const bool do_stats = (blockIdx.y == 0);         // uniform branch
  const float* __restrict__ zrow = z + (size_t)j * Z_D;
  for (int i4 = 0; i4 < Z_D; i4 += 4) {
    const float4 zv = *(const float4*)(zrow + i4);
    if (do_stats) {
      s += zv.x + zv.y + zv.z + zv.w;
      q += zv.x * zv.x + zv.y * zv.y + zv.z * zv.z + zv.w * zv.w;
    }
#pragma unroll
    for (int kk = 0; kk < 8; ++kk) {
      const float4 pv = *(const float4*)(pt + kk * Z_D + i4);  // LDS broadcast
      acc[kk] += zv.x * pv.x + zv.y * pv.y + zv.z * pv.z + zv.w * pv.w;
    }
  }
  float4 lo = make_float4(acc[0], acc[1], acc[2], acc[3]);
  float4 hi = make_float4(acc[4], acc[5], acc[6], acc[7]);
  *(float4*)(GT + (size_t)j * GT_S + k0) = lo;     // 32B contiguous in k
  *(float4*)(GT + (size_t)j * GT_S + k0 + 4) = hi;
  if (do_stats) {
    zz[j] = q;
    sz[j] = s;
    w[j] = q - TWO_EPS * s;    // per-j part of pdist(prox, z)
  }
}

// --- kC: one wave per anchor (argmin proxy -> bucket argmax -> logsumexp) --
__global__ void kC(const float* __restrict__ zz, const float* __restrict__ sz,
                   const float* __restrict__ w, const int* __restrict__ yrel,
                   const float* __restrict__ pp, const float* __restrict__ sp,
                   const float* __restrict__ GT,
                   const int* __restrict__ cnt, const int* __restrict__ bucket,
                   float* __restrict__ acc) {
  __shared__ float part[4];
  const int wv = threadIdx.x >> 6;
  const int wid = blockIdx.x * 4 + wv;
  const int lane = threadIdx.x & 63;
  float loss = 0.0f;
  if (wid < A_N) {
    const int i = 3 * wid;                 // anchor sample index
    const float zzi = zz[i], szi = sz[i];
    const int cls = yrel[i];
    const int k2 = lane + 64;

    // --- step a: nearest proxy to anchor (argmin, first-index tie-break) ---
    const float* __restrict__ GTi = GT + (size_t)i * GT_S;
    float v1 = fmaxf(zzi + pp[lane] - 2.0f * GTi[lane] +
                     TWO_EPS * (szi - sp[lane]) + ZEPS2, 0.0f);
    int i1 = lane;
    if (k2 < P_N) {
      float v2 = fmaxf(zzi + pp[k2] - 2.0f * GTi[k2] +
                       TWO_EPS * (szi - sp[k2]) + ZEPS2, 0.0f);
      if (v2 < v1) { v1 = v2; i1 = k2; }
    }
#pragma unroll
    for (int off = 1; off < 64; off <<= 1) {
      float ov = __shfl_xor(v1, off, 64);
      int oi = __shfl_xor(i1, off, 64);
      if (ov < v1 || (ov == v1 && oi < i1)) { v1 = ov; i1 = oi; }
    }
    const int p = i1;

    // --- step b: hardest positive among same-class suffix (class bucket) ---
    const float cp = pp[p] + TWO_EPS * sp[p] + ZEPS2;  // per-proxy constant
    const int n = cnt[cls];
    const int* __restrict__ bk = bucket + cls * BCAP;
    float best = -INFINITY;
    int bestj = 0x7fffffff;
    for (int t = lane; t < n; t += 64) {
      const int j = bk[t];
      if (j >= i) {
        const float v = fmaxf(cp + w[j] - 2.0f * GT[(size_t)j * GT_S + p], 0.0f);
        if (v > best || (v == best && j < bestj)) { best = v; bestj = j; }
      }
    }
#pragma unroll
    for (int off = 1; off < 64; off <<= 1) {
      float ov = __shfl_xor(best, off, 64);
      int oj = __shfl_xor(bestj, off, 64);
      if (ov > best || (ov == best && oj < bestj)) { best = ov; bestj = oj; }
    }
    const float Dp = sqrtf(best);
    const int jp = bestj;

    // --- step c: logsumexp(-D_n) over proxies ---
    const float zzj = zz[jp], szj = sz[jp];
    const float* __restrict__ GTj = GT + (size_t)jp * GT_S;
    float d1 = sqrtf(fmaxf(zzj + pp[lane] - 2.0f * GTj[lane] +
                           TWO_EPS * (szj - sp[lane]) + ZEPS2, 0.0f));
    float d2 = INFINITY;
    if (k2 < P_N)
      d2 = sqrtf(fmaxf(zzj + pp[k2] - 2.0f * GTj[k2] +
                       TWO_EPS * (szj - sp[k2]) + ZEPS2, 0.0f));
    const float m = wave_min(fminf(d1, d2));
    float ssum = expf(m - d1) + ((k2 < P_N) ? expf(m - d2) : 0.0f);
    ssum = wave_sum(ssum);
    loss = Dp - m + logf(ssum);
  }
  if (lane == 0) part[wv] = (wid < A_N) ? loss : 0.0f;
  __syncthreads();
  if (threadIdx.x == 0)
    atomicAdd(acc, part[0] + part[1] + part[2] + part[3]);
}

// --- kF: mean --------------------------------------------------------------
__global__ void kF(const float* __restrict__ acc, float* __restrict__ out) {
  out[0] = acc[0] * (1.0f / (float)A_N);
}

extern "C" void kernel_launch(void* const* d_in, const int* in_sizes, int n_in,
                              void* d_out, int out_size, void* d_ws, size_t ws_size,
                              hipStream_t stream) {
  const float* z = (const float*)d_in[0];      // [8192,128] f32
  const int* y_idx = (const int*)d_in[1];      // [8192] i32
  const float* prox = (const float*)d_in[2];   // [93,128] f32
  const int* y_map = (const int*)d_in[3];      // [62] i32
  float* out = (float*)d_out;

  // workspace layout (bytes) — total ~3.39 MB
  char* ws = (char*)d_ws;
  float* prxn   = (float*)(ws + 0);            // 96*128*4 = 49152 (padded)
  float* pp     = (float*)(ws + 49152);        // -> 49664
  float* sp     = (float*)(ws + 49664);        // -> 50176
  int*   invmap = (int*)  (ws + 50176);        // 64*4 -> 50432
  float* zz     = (float*)(ws + 50432);        // 8192*4 -> 83200
  float* sz     = (float*)(ws + 83200);        // -> 115968
  float* w      = (float*)(ws + 115968);       // -> 148736
  int*   yrel   = (int*)  (ws + 148736);       // -> 181504
  int*   cnt    = (int*)  (ws + 181504);       // 62*4 -> 181760
  int*   bkt    = (int*)  (ws + 181760);       // 62*256*4 -> 245248
  float* GT     = (float*)(ws + 245248);       // 8192*96*4 -> 3390976
  float* acc    = (float*)(ws + 3390976);      // 4

  kP<<<P_N, 64, 0, stream>>>(prox, prxn, pp, sp, y_map, invmap, acc);
  kB<<<NCLS, 256, 0, stream>>>(y_idx, invmap, yrel, cnt, bkt);
  kG<<<dim3(B_N / 256, 96 / 8), 256, 0, stream>>>(z, prxn, GT, zz, sz, w);
  kC<<<(A_N + 3) / 4, 256, 0, stream>>>(zz, sz, w, yrel, pp, sp, GT,
                                        cnt, bkt, acc);
  kF<<<1, 1, 0, stream>>>(acc, out);
}